// Round 4
// baseline (544.364 us; speedup 1.0000x reference)
//
#include <hip/hip_runtime.h>

// BatchSRU (L=2048,B=8,D=128,NB=16) v3:
//  k_wprep: W -> fp16 hi/lo MFMA-fragment order
//  k_prep : x (L,B,D,NB) fp32 -> XP[k][b][l][d] packed u32 (fp16 hi | lo<<16)
//  k_sru  : BARRIER-FREE fused GEMM + in-register shuffle scan.
//           Each wave owns 16 output cols of one (b,k,seg); writes h directly
//           to out (original layout, L2-merged across co-XCD k-blocks).
//  k_comb : chain segment summaries -> Cin
//  k_fix  : out[l<64 rows of each seg] += rP * Cin  (RMW, small)

typedef float f32x4 __attribute__((ext_vector_type(4)));
typedef _Float16 f16x8 __attribute__((ext_vector_type(8)));
typedef unsigned int u32;
typedef u32 u32x4 __attribute__((ext_vector_type(4)));
typedef unsigned short u16;

__device__ inline u32 pack_hl(float x) {
  _Float16 h = (_Float16)x;
  _Float16 l = (_Float16)(x - (float)h);
  u32 uh = (u32)__builtin_bit_cast(u16, h);
  u32 ul = (u32)__builtin_bit_cast(u16, l);
  return uh | (ul << 16);
}
__device__ inline float unpack_hl(u32 v) {
  return (float)__builtin_bit_cast(_Float16, (u16)(v & 0xffffu)) +
         (float)__builtin_bit_cast(_Float16, (u16)(v >> 16));
}

// ---------------- W fragment pre-pack (unchanged, grid 384) ----------------
__global__ __launch_bounds__(256) void k_wprep(const float* __restrict__ W,
                                               _Float16* __restrict__ Wfh,
                                               _Float16* __restrict__ Wfl) {
  int e = blockIdx.x * 256 + threadIdx.x;  // 0..98303
  int lam = e & 63;
  int t = e >> 6;
  int s = t & 3; t >>= 2;
  int w = t & 7; t >>= 3;
  int cti = t % 3;
  int k = t / 3;
  const float* Wp = W + (size_t)k * 128 * 384 + (size_t)(cti * 128 + 16 * w + (lam & 15));
  int row0 = 32 * s + 8 * (lam >> 4);
  size_t o = (size_t)e * 8;
#pragma unroll
  for (int ii = 0; ii < 8; ++ii) {
    float v = Wp[(size_t)(row0 + ii) * 384];
    _Float16 h = (_Float16)v;
    Wfh[o + ii] = h;
    Wfl[o + ii] = (_Float16)(v - (float)h);
  }
}

// ---------------- x transpose + pack (unchanged) ----------------
__global__ __launch_bounds__(256) void k_prep(const float* __restrict__ x,
                                              u32* __restrict__ XP) {
  __shared__ u32 S[2][16 * 193];
  const int bid = blockIdx.x;
  const int b = bid & 7, l0 = (bid >> 3) * 4;
  const int t = threadIdx.x;
  const int d0 = t >> 1, kc = t & 1;
  const int kk = t >> 4, dc = t & 15;
  const int pw = d0 + 4 * (d0 >> 3);
  for (int li = 0; li < 4; ++li) {
    const int l = l0 + li;
    const float* src = x + ((size_t)(l * 8 + b) * 128 + d0) * 16 + kc * 8;
    f32x4 v0 = *(const f32x4*)src;
    f32x4 v1 = *(const f32x4*)(src + 4);
    u32* Sw = S[li & 1];
#pragma unroll
    for (int i = 0; i < 8; ++i) {
      float xv = (i < 4) ? v0[i] : v1[i - 4];
      Sw[(kc * 8 + i) * 193 + pw] = pack_hl(xv);
    }
    __syncthreads();
    u32 vv[8];
#pragma unroll
    for (int e = 0; e < 8; ++e) vv[e] = Sw[kk * 193 + 12 * dc + e];
    size_t o = ((size_t)(kk * 8 + b) * 2048 + l) * 128 + dc * 8;
    *(u32x4*)(XP + o) = (u32x4){vv[0], vv[1], vv[2], vv[3]};
    *(u32x4*)(XP + o + 4) = (u32x4){vv[4], vv[5], vv[6], vv[7]};
  }
}

// ---------------- fused GEMM + in-register scan, no barriers ----------------
// grid 2048, 256 thr (4 waves). bid: xcd=bid&7, idx=bid>>3;
// group (b,seg) = xcd*8 + (idx>>5); sub=idx&31: k=sub>>1, half=sub&1.
// wave column-group wcol = half*4 + waveid; lane (n,g) owns rows 4g+e, col 16*wcol+n.
__global__ __launch_bounds__(256, 3) void k_sru(
    const u32* __restrict__ XP, const _Float16* __restrict__ Wfh,
    const _Float16* __restrict__ Wfl, const float* __restrict__ bias,
    float* __restrict__ out, _Float16* __restrict__ rP,
    float* __restrict__ Pseg, float* __restrict__ Cend) {
  const int bid = blockIdx.x;
  const int xcd = bid & 7, idx = bid >> 3;
  const int grp = xcd * 8 + (idx >> 5);
  const int sub = idx & 31;
  const int b = grp & 7, seg = grp >> 3;
  const int k = sub >> 1, half = sub & 1;
  const int tid = threadIdx.x, wl = tid & 63;
  const int wcol = half * 4 + (tid >> 6);
  const int n = wl & 15, g = wl >> 4;
  const int col = 16 * wcol + n;

  // W fragments in registers (full 16-col slice of all 3 parts)
  f16x8 BH[3][4], BL[3][4];
#pragma unroll
  for (int cti = 0; cti < 3; ++cti)
#pragma unroll
    for (int s2 = 0; s2 < 4; ++s2) {
      size_t off = ((((size_t)(k * 3 + cti) * 8 + wcol) * 4 + s2) * 64 + wl) * 8;
      BH[cti][s2] = *(const f16x8*)(Wfh + off);
      BL[cti][s2] = *(const f16x8*)(Wfl + off);
    }
  const float biasF = bias[k * 256 + col];
  const float biasR = bias[k * 256 + 128 + col];

  const u32* Xbase = XP + ((size_t)(k * 8 + b) * 2048 + (size_t)seg * 256) * 128;

  float cseg = 0.f, carryP = 1.f;

  for (int t = 0; t < 16; ++t) {
    // ---- A-fragment loads (coalesced dwordx4 pairs) ----
    u32x4 q[8];
#pragma unroll
    for (int s2 = 0; s2 < 4; ++s2) {
      const u32* p = Xbase + (size_t)(t * 16 + n) * 128 + 32 * s2 + 8 * g;
      q[2 * s2] = *(const u32x4*)p;
      q[2 * s2 + 1] = *(const u32x4*)(p + 4);
    }
    // ---- highway x values for this lane's 4 rows ----
    float xv[4];
#pragma unroll
    for (int e = 0; e < 4; ++e)
      xv[e] = unpack_hl(Xbase[(size_t)(t * 16 + 4 * g + e) * 128 + col]);

    // ---- GEMM (verbatim R3 math) ----
    f32x4 a0 = {0.f, 0.f, 0.f, 0.f}, a1 = a0, a2 = a0;
#pragma unroll
    for (int s2 = 0; s2 < 4; ++s2) {
      u32x4 q0 = q[2 * s2], q1 = q[2 * s2 + 1];
      u32 h0 = __builtin_amdgcn_perm(q0[1], q0[0], 0x05040100u);
      u32 h1 = __builtin_amdgcn_perm(q0[3], q0[2], 0x05040100u);
      u32 h2 = __builtin_amdgcn_perm(q1[1], q1[0], 0x05040100u);
      u32 h3 = __builtin_amdgcn_perm(q1[3], q1[2], 0x05040100u);
      u32 l0 = __builtin_amdgcn_perm(q0[1], q0[0], 0x07060302u);
      u32 l1 = __builtin_amdgcn_perm(q0[3], q0[2], 0x07060302u);
      u32 l2 = __builtin_amdgcn_perm(q1[1], q1[0], 0x07060302u);
      u32 l3 = __builtin_amdgcn_perm(q1[3], q1[2], 0x07060302u);
      f16x8 ah = __builtin_bit_cast(f16x8, (u32x4){h0, h1, h2, h3});
      f16x8 al = __builtin_bit_cast(f16x8, (u32x4){l0, l1, l2, l3});
      a0 = __builtin_amdgcn_mfma_f32_16x16x32_f16(ah, BH[0][s2], a0, 0, 0, 0);
      a1 = __builtin_amdgcn_mfma_f32_16x16x32_f16(ah, BH[1][s2], a1, 0, 0, 0);
      a2 = __builtin_amdgcn_mfma_f32_16x16x32_f16(ah, BH[2][s2], a2, 0, 0, 0);
      a0 = __builtin_amdgcn_mfma_f32_16x16x32_f16(al, BH[0][s2], a0, 0, 0, 0);
      a1 = __builtin_amdgcn_mfma_f32_16x16x32_f16(al, BH[1][s2], a1, 0, 0, 0);
      a2 = __builtin_amdgcn_mfma_f32_16x16x32_f16(al, BH[2][s2], a2, 0, 0, 0);
      a0 = __builtin_amdgcn_mfma_f32_16x16x32_f16(ah, BL[0][s2], a0, 0, 0, 0);
      a1 = __builtin_amdgcn_mfma_f32_16x16x32_f16(ah, BL[1][s2], a1, 0, 0, 0);
      a2 = __builtin_amdgcn_mfma_f32_16x16x32_f16(ah, BL[2][s2], a2, 0, 0, 0);
    }

    // ---- gates ----
    float f[4], r[4];
#pragma unroll
    for (int e = 0; e < 4; ++e) {
      f[e] = 1.f / (1.f + __expf(-(a1[e] + biasF)));
      r[e] = 1.f / (1.f + __expf(-(a2[e] + biasR)));
    }

    // ---- per-lane 4-row compose: c_out = Cl + Pl * c_in ----
    float Pl = f[0] * f[1] * f[2] * f[3];
    float Cl = 0.f;
#pragma unroll
    for (int e = 0; e < 4; ++e) Cl = f[e] * Cl + (1.f - f[e]) * a0[e];

    // ---- inclusive scan over g (lanes n, n+16, n+32, n+48) ----
    float Pi = Pl, Ci = Cl;
    {
      float Pp = __shfl(Pi, wl - 16);
      float Cp = __shfl(Ci, wl - 16);
      if (g >= 1) { Ci = Ci + Pi * Cp; Pi = Pi * Pp; }
    }
    {
      float Pp = __shfl(Pi, wl - 32);
      float Cp = __shfl(Ci, wl - 32);
      if (g >= 2) { Ci = Ci + Pi * Cp; Pi = Pi * Pp; }
    }
    // exclusive prefix for this lane
    float Pe = __shfl(Pi, wl - 16);
    float Ce = __shfl(Ci, wl - 16);
    if (g == 0) { Pe = 1.f; Ce = 0.f; }
    float c = Ce + Pe * cseg;
    float p = carryP * Pe;
    // carry update from g==3 inclusive
    float Pall = __shfl(Pi, n + 48);
    float Call = __shfl(Ci, n + 48);
    cseg = Call + Pall * cseg;
    carryP = carryP * Pall;

    // ---- rows: recurrence + highway + stores ----
#pragma unroll
    for (int e = 0; e < 4; ++e) {
      c = f[e] * c + (1.f - f[e]) * a0[e];
      p = p * f[e];
      float h = xv[e] + r[e] * (c - xv[e]);
      int row = t * 16 + 4 * g + e;
      out[((size_t)((seg * 256 + row) * 8 + b)) * 2048 + col * 16 + k] = h;
      if (t < 4)
        rP[((((size_t)(b * 8 + seg) * 64) + row) * 128 + col) * 16 + k] =
            (_Float16)(r[e] * p);
    }
  }

  if (g == 0) {
    size_t o = (size_t)seg * 16384 + (size_t)(k * 8 + b) * 128 + col;
    Pseg[o] = carryP;
    Cend[o] = cseg;
  }
}

// ---------------- segment chain (unchanged) ----------------
__global__ __launch_bounds__(256) void k_comb(const float* __restrict__ Pseg,
                                              const float* __restrict__ Cend,
                                              float* __restrict__ Cin) {
  int ch = blockIdx.x * 256 + threadIdx.x;
  float c = 0.f;
#pragma unroll
  for (int s = 0; s < 8; ++s) {
    Cin[s * 16384 + ch] = c;
    c = Cend[s * 16384 + ch] + Pseg[s * 16384 + ch] * c;
  }
}

// ---------------- correction RMW: out += rP * Cin for l_loc < 64 ----------------
// grid 1024: grp = bid>>4 -> (b,seg); q = bid&15 -> rows q*4..q*4+3.
__global__ __launch_bounds__(256) void k_fix(float* __restrict__ out,
                                             const _Float16* __restrict__ rP,
                                             const float* __restrict__ Cin) {
  const int bid = blockIdx.x;
  const int grp = bid >> 4, q = bid & 15;
  const int b = grp & 7, seg = grp >> 3;
  const int tid = threadIdx.x;
  __shared__ float Cs[2048];  // [k][d]
  for (int i = tid; i < 2048; i += 256) {
    int kk = i >> 7, d = i & 127;
    Cs[i] = Cin[(size_t)seg * 16384 + (size_t)(kk * 8 + b) * 128 + d];
  }
  __syncthreads();
  const int d = tid >> 1, kh = (tid & 1) * 8;
  for (int rr = 0; rr < 4; ++rr) {
    int row = q * 4 + rr;
    size_t ob = ((size_t)((seg * 256 + row) * 8 + b)) * 2048 + d * 16 + kh;
    f32x4 o0 = *(f32x4*)(out + ob);
    f32x4 o1 = *(f32x4*)(out + ob + 4);
    const _Float16* rp =
        rP + ((((size_t)(b * 8 + seg) * 64) + row) * 128 + d) * 16 + kh;
    f16x8 rv = *(const f16x8*)rp;
#pragma unroll
    for (int e = 0; e < 4; ++e) {
      o0[e] += (float)rv[e] * Cs[(kh + e) * 128 + d];
      o1[e] += (float)rv[4 + e] * Cs[(kh + 4 + e) * 128 + d];
    }
    *(f32x4*)(out + ob) = o0;
    *(f32x4*)(out + ob + 4) = o1;
  }
}

extern "C" void kernel_launch(void* const* d_in, const int* in_sizes, int n_in,
                              void* d_out, int out_size, void* d_ws, size_t ws_size,
                              hipStream_t stream) {
  (void)in_sizes; (void)n_in; (void)out_size; (void)ws_size;
  const float* x = (const float*)d_in[0];
  const float* W = (const float*)d_in[1];
  const float* bias = (const float*)d_in[2];
  float* out = (float*)d_out;
  char* ws = (char*)d_ws;
  u32* XP        = (u32*)ws;                          // 134,217,728 B
  _Float16* Wfh  = (_Float16*)(ws + 134217728);       //   1,572,864 B
  _Float16* Wfl  = (_Float16*)(ws + 135790592);       //   1,572,864 B
  _Float16* rPp  = (_Float16*)(ws + 137363456);       //  16,777,216 B
  float* Pseg    = (float*)(ws + 154140672);          //     524,288 B
  float* Cend    = (float*)(ws + 154664960);          //     524,288 B
  float* Cin     = (float*)(ws + 155189248);          //     524,288 B

  k_wprep<<<384, 256, 0, stream>>>(W, Wfh, Wfl);
  k_prep<<<4096, 256, 0, stream>>>(x, XP);
  k_sru<<<2048, 256, 0, stream>>>(XP, Wfh, Wfl, bias, out, rPp, Pseg, Cend);
  k_comb<<<64, 256, 0, stream>>>(Pseg, Cend, Cin);
  k_fix<<<1024, 256, 0, stream>>>(out, rPp, Cin);
}